// Round 6
// baseline (454.382 us; speedup 1.0000x reference)
//
#include <hip/hip_runtime.h>
#include <math.h>

#define NROWS 65536
#define DDIM  64
#define KCB   1024

// ---------------------------------------------------------------------------
// Kernel 1: C2[j] = ||W_j||^2 via numpy pairwise-sum emulation (n=64: 8 accs).
// ---------------------------------------------------------------------------
__global__ void vq_c2_kernel(const float* __restrict__ W, float* __restrict__ C2) {
    int j = blockIdx.x * blockDim.x + threadIdx.x;
    if (j >= KCB) return;
    const float* w = W + (size_t)j * DDIM;
    float r[8];
#pragma unroll
    for (int m = 0; m < 8; ++m) r[m] = __fmul_rn(w[m], w[m]);
#pragma unroll
    for (int i = 8; i < 64; i += 8) {
#pragma unroll
        for (int m = 0; m < 8; ++m)
            r[m] = __fadd_rn(r[m], __fmul_rn(w[i + m], w[i + m]));
    }
    float res = __fadd_rn(
        __fadd_rn(__fadd_rn(r[0], r[1]), __fadd_rn(r[2], r[3])),
        __fadd_rn(__fadd_rn(r[4], r[5]), __fadd_rn(r[6], r[7])));
    C2[j] = res;
}

// ---------------------------------------------------------------------------
// Kernel 2: main argmin. ONE WAVE PER BLOCK (64 threads); lane l owns row
// blockIdx*64 + l; the wave scans ALL 1024 codes in ascending order.
//
// Delivery economics (learned rounds 0-5, all measured):
//  - LDS / VMEM broadcast of W pays 64 lanes x 16B = 1KB per b128 through a
//    ~128B/clk per-CU return port -> LDS-pipe-bound at ~207us (round 5).
//  - Scalar s_load broadcasts 256B once per wave per code -> the only cheap
//    path (round 0: 168us). Its cost there was K$ thrash: 4 waves/block each
//    streamed a DIFFERENT 64KB W slice through the 16KB scalar cache ->
//    every code missed to L2 behind a serializing lgkmcnt(0).
//  - This version: every resident wave streams the SAME 256KB W sequence.
//    The leading wave misses and stalls (self-synchronizing back into the
//    pack); trailers hit K$ (~25cyc). Amortized miss ~= L2lat/waves_per_CU.
//
// Single wave owns each row end-to-end -> zero LDS, zero barriers, zero
// reduction; argmin is a register scan with strict < over ascending j
// (first-index tie-break preserved exactly).
//
// Math byte-identical to the verified anchor: CL = sequential fp32 FMA chain
// k=0..63, dist = (L2 - 2*CL) + C2[j], L2 via numpy pairwise-8 sum.
// ---------------------------------------------------------------------------
__global__ void __launch_bounds__(64, 4)
vq_main_kernel(const float* __restrict__ x, const float* __restrict__ W,
               const float* __restrict__ C2, int* __restrict__ cls_i,
               float* __restrict__ cls_f) {
    const int lane = threadIdx.x;
    const int row  = blockIdx.x * 64 + lane;

    // Load this row of x into registers (16 x float4).
    const float* xr = x + (size_t)row * DDIM;
    float xv[64];
#pragma unroll
    for (int k = 0; k < 64; k += 4) {
        float4 v = *(const float4*)(xr + k);
        xv[k] = v.x; xv[k + 1] = v.y; xv[k + 2] = v.z; xv[k + 3] = v.w;
    }

    // L2 = numpy pairwise sum of x*x (n=64).
    float r[8];
#pragma unroll
    for (int m = 0; m < 8; ++m) r[m] = __fmul_rn(xv[m], xv[m]);
#pragma unroll
    for (int i = 8; i < 64; i += 8) {
#pragma unroll
        for (int m = 0; m < 8; ++m)
            r[m] = __fadd_rn(r[m], __fmul_rn(xv[i + m], xv[i + m]));
    }
    const float L2 = __fadd_rn(
        __fadd_rn(__fadd_rn(r[0], r[1]), __fadd_rn(r[2], r[3])),
        __fadd_rn(__fadd_rn(r[4], r[5]), __fadd_rn(r[6], r[7])));

    float best = INFINITY;
    int   bidx = 0;
#pragma unroll 1
    for (int j = 0; j < KCB; ++j) {
        const float* wr = W + (size_t)j * DDIM;  // wave-uniform -> s_load
        float acc = 0.0f;
#pragma unroll
        for (int k = 0; k < 64; ++k)
            acc = __builtin_fmaf(xv[k], wr[k], acc);
        const float dist = __fadd_rn(__fsub_rn(L2, __fmul_rn(2.0f, acc)), C2[j]);
        if (dist < best) { best = dist; bidx = j; }  // strict <: keep lowest j
    }

    cls_i[row] = bidx;
    cls_f[row] = (float)bidx;  // harness reads indices as fp32
}

// ---------------------------------------------------------------------------
// Kernel 3: gather quantized = W[closest]. 16 threads/row, float4 each.
// ---------------------------------------------------------------------------
__global__ void vq_gather_kernel(const float* __restrict__ W,
                                 const int* __restrict__ cls,
                                 float* __restrict__ outq) {
    const int t = blockIdx.x * blockDim.x + threadIdx.x;
    const int i = t >> 4;
    const int q = t & 15;
    const int j = cls[i];
    const float4 v = *(const float4*)(W + (size_t)j * DDIM + q * 4);
    *(float4*)(outq + (size_t)i * DDIM + q * 4) = v;
}

extern "C" void kernel_launch(void* const* d_in, const int* in_sizes, int n_in,
                              void* d_out, int out_size, void* d_ws, size_t ws_size,
                              hipStream_t stream) {
    const float* x = (const float*)d_in[0];
    const float* W = (const float*)d_in[1];

    float* outq = (float*)d_out;                        // N*D quantized
    float* outi = (float*)d_out + (size_t)NROWS * DDIM; // N indices as float

    float* C2  = (float*)d_ws;                          // 4 KB
    int*   cls = (int*)((char*)d_ws + 4096);            // 256 KB

    hipLaunchKernelGGL(vq_c2_kernel, dim3(KCB / 256), dim3(256), 0, stream, W, C2);
    hipLaunchKernelGGL(vq_main_kernel, dim3(NROWS / 64), dim3(64), 0, stream,
                       x, W, C2, cls, outi);
    hipLaunchKernelGGL(vq_gather_kernel, dim3((NROWS * 16) / 256), dim3(256), 0,
                       stream, W, cls, outq);
}

// Round 7
// 322.927 us; speedup vs baseline: 1.4071x; 1.4071x over previous
//
#include <hip/hip_runtime.h>
#include <math.h>

#define NROWS 65536
#define DDIM  64
#define KCB   1024

// ---------------------------------------------------------------------------
// Kernel 1: C2[j] = ||W_j||^2 via numpy pairwise-sum emulation (n=64: 8 accs).
// ---------------------------------------------------------------------------
__global__ void vq_c2_kernel(const float* __restrict__ W, float* __restrict__ C2) {
    int j = blockIdx.x * blockDim.x + threadIdx.x;
    if (j >= KCB) return;
    const float* w = W + (size_t)j * DDIM;
    float r[8];
#pragma unroll
    for (int m = 0; m < 8; ++m) r[m] = __fmul_rn(w[m], w[m]);
#pragma unroll
    for (int i = 8; i < 64; i += 8) {
#pragma unroll
        for (int m = 0; m < 8; ++m)
            r[m] = __fadd_rn(r[m], __fmul_rn(w[i + m], w[i + m]));
    }
    float res = __fadd_rn(
        __fadd_rn(__fadd_rn(r[0], r[1]), __fadd_rn(r[2], r[3])),
        __fadd_rn(__fadd_rn(r[4], r[5]), __fadd_rn(r[6], r[7])));
    C2[j] = res;
}

// ---------------------------------------------------------------------------
// Kernel 2: main argmin. Round-0 body, 2x the wave count.
// Block = 512 threads = 8 WAVES, owns 64 rows (lane l -> row blockIdx*64+l);
// wave s scans codes [s*128, s*128+128). Grid = 1024 blocks = 4 blocks/CU
// x 8 waves = 32 waves/CU (hardware max), vs round-0's 16.
//
// Model (consistent with rounds 0..6): chip FMA issue floor = 54.6us; the
// per-code wave-uniform s_load of a 256B W row costs ~250cyc of latency that
// only cross-wave interleave can hide. Waves/SIMD: 1 -> 390us (round 6),
// 4 -> 168us (round 0). This round: 8 waves/SIMD. W delivery stays on the
// scalar path (the only free broadcast; LDS/VMEM broadcast = 1KB/read
// through the vector return bus, measured 207us in round 5).
//
// Math byte-identical to the verified anchor: CL = sequential fp32 FMA chain
// k=0..63, dist = (L2 - 2*CL) + C2[j], L2 via numpy pairwise-8 sum.
// Tie-break: strict < over ascending j within a wave; cross-wave combine in
// ascending s (= ascending code ranges) keeps the first-index semantics.
// ---------------------------------------------------------------------------
__global__ void __launch_bounds__(512, 8)
vq_main_kernel(const float* __restrict__ x, const float* __restrict__ W,
               const float* __restrict__ C2, int* __restrict__ cls_i,
               float* __restrict__ cls_f) {
    __shared__ float s_bd[8][64];
    __shared__ int   s_bi[8][64];

    const int lane = threadIdx.x & 63;
    const int s    = __builtin_amdgcn_readfirstlane(threadIdx.x >> 6);
    const int row  = blockIdx.x * 64 + lane;

    // Load this row of x into registers (16 x float4).
    const float* xr = x + (size_t)row * DDIM;
    float xv[64];
#pragma unroll
    for (int k = 0; k < 64; k += 4) {
        float4 v = *(const float4*)(xr + k);
        xv[k] = v.x; xv[k + 1] = v.y; xv[k + 2] = v.z; xv[k + 3] = v.w;
    }

    // L2 = numpy pairwise sum of x*x (n=64).
    float r[8];
#pragma unroll
    for (int m = 0; m < 8; ++m) r[m] = __fmul_rn(xv[m], xv[m]);
#pragma unroll
    for (int i = 8; i < 64; i += 8) {
#pragma unroll
        for (int m = 0; m < 8; ++m)
            r[m] = __fadd_rn(r[m], __fmul_rn(xv[i + m], xv[i + m]));
    }
    const float L2 = __fadd_rn(
        __fadd_rn(__fadd_rn(r[0], r[1]), __fadd_rn(r[2], r[3])),
        __fadd_rn(__fadd_rn(r[4], r[5]), __fadd_rn(r[6], r[7])));

    float best = INFINITY;
    int   bidx = 0;
    const int j0 = s * 128;
#pragma unroll 1
    for (int jj = 0; jj < 128; ++jj) {
        const int j = j0 + jj;
        const float* wr = W + (size_t)j * DDIM;  // wave-uniform -> s_load
        float acc = 0.0f;
#pragma unroll
        for (int k = 0; k < 64; ++k)
            acc = __builtin_fmaf(xv[k], wr[k], acc);
        const float dist = __fadd_rn(__fsub_rn(L2, __fmul_rn(2.0f, acc)), C2[j]);
        if (dist < best) { best = dist; bidx = j; }  // strict <: keep lowest j
    }

    s_bd[s][lane] = best;
    s_bi[s][lane] = bidx;
    __syncthreads();

    if (s == 0) {
        float b  = s_bd[0][lane];
        int   bi = s_bi[0][lane];
#pragma unroll
        for (int t = 1; t < 8; ++t) {
            const float d = s_bd[t][lane];
            if (d < b) { b = d; bi = s_bi[t][lane]; }  // ascending j-ranges
        }
        cls_i[row] = bi;
        cls_f[row] = (float)bi;  // harness reads indices as fp32
    }
}

// ---------------------------------------------------------------------------
// Kernel 3: gather quantized = W[closest]. 16 threads/row, float4 each.
// ---------------------------------------------------------------------------
__global__ void vq_gather_kernel(const float* __restrict__ W,
                                 const int* __restrict__ cls,
                                 float* __restrict__ outq) {
    const int t = blockIdx.x * blockDim.x + threadIdx.x;
    const int i = t >> 4;
    const int q = t & 15;
    const int j = cls[i];
    const float4 v = *(const float4*)(W + (size_t)j * DDIM + q * 4);
    *(float4*)(outq + (size_t)i * DDIM + q * 4) = v;
}

extern "C" void kernel_launch(void* const* d_in, const int* in_sizes, int n_in,
                              void* d_out, int out_size, void* d_ws, size_t ws_size,
                              hipStream_t stream) {
    const float* x = (const float*)d_in[0];
    const float* W = (const float*)d_in[1];

    float* outq = (float*)d_out;                        // N*D quantized
    float* outi = (float*)d_out + (size_t)NROWS * DDIM; // N indices as float

    float* C2  = (float*)d_ws;                          // 4 KB
    int*   cls = (int*)((char*)d_ws + 4096);            // 256 KB

    hipLaunchKernelGGL(vq_c2_kernel, dim3(KCB / 256), dim3(256), 0, stream, W, C2);
    hipLaunchKernelGGL(vq_main_kernel, dim3(NROWS / 64), dim3(512), 0, stream,
                       x, W, C2, cls, outi);
    hipLaunchKernelGGL(vq_gather_kernel, dim3((NROWS * 16) / 256), dim3(256), 0,
                       stream, W, cls, outq);
}

// Round 8
// 277.537 us; speedup vs baseline: 1.6372x; 1.1635x over previous
//
#include <hip/hip_runtime.h>
#include <math.h>

#define NROWS 65536
#define DDIM  64
#define KCB   1024

// ---------------------------------------------------------------------------
// Kernel 1: C2[j] = ||W_j||^2 via numpy pairwise-sum emulation (n=64: 8 accs).
// ---------------------------------------------------------------------------
__global__ void vq_c2_kernel(const float* __restrict__ W, float* __restrict__ C2) {
    int j = blockIdx.x * blockDim.x + threadIdx.x;
    if (j >= KCB) return;
    const float* w = W + (size_t)j * DDIM;
    float r[8];
#pragma unroll
    for (int m = 0; m < 8; ++m) r[m] = __fmul_rn(w[m], w[m]);
#pragma unroll
    for (int i = 8; i < 64; i += 8) {
#pragma unroll
        for (int m = 0; m < 8; ++m)
            r[m] = __fadd_rn(r[m], __fmul_rn(w[i + m], w[i + m]));
    }
    float res = __fadd_rn(
        __fadd_rn(__fadd_rn(r[0], r[1]), __fadd_rn(r[2], r[3])),
        __fadd_rn(__fadd_rn(r[4], r[5]), __fadd_rn(r[6], r[7])));
    C2[j] = res;
}

// ---------------------------------------------------------------------------
// Kernel 1b: L2[i] = ||x_i||^2, bit-identical pairwise-8 sum (was in-kernel).
// ---------------------------------------------------------------------------
__global__ void vq_l2_kernel(const float* __restrict__ x, float* __restrict__ L2b) {
    const int i = blockIdx.x * blockDim.x + threadIdx.x;  // one row per thread
    const float* xr = x + (size_t)i * DDIM;
    float xv[64];
#pragma unroll
    for (int k = 0; k < 64; k += 4) {
        float4 v = *(const float4*)(xr + k);
        xv[k] = v.x; xv[k + 1] = v.y; xv[k + 2] = v.z; xv[k + 3] = v.w;
    }
    float r[8];
#pragma unroll
    for (int m = 0; m < 8; ++m) r[m] = __fmul_rn(xv[m], xv[m]);
#pragma unroll
    for (int i2 = 8; i2 < 64; i2 += 8) {
#pragma unroll
        for (int m = 0; m < 8; ++m)
            r[m] = __fadd_rn(r[m], __fmul_rn(xv[i2 + m], xv[i2 + m]));
    }
    L2b[i] = __fadd_rn(
        __fadd_rn(__fadd_rn(r[0], r[1]), __fadd_rn(r[2], r[3])),
        __fadd_rn(__fadd_rn(r[4], r[5]), __fadd_rn(r[6], r[7])));
}

// ---------------------------------------------------------------------------
// Kernel 2: main argmin, TRANSPOSED decomposition (lane = code, stream = x).
//
// Measured delivery economics (rounds 0-7): streaming W per code through ANY
// broadcast path is the bottleneck — scalar K$ fill caps at ~2.7 B/cyc/CU
// (r0: 1MB/CU -> 168us; r6 serialized fills -> 390us) and LDS broadcast pays
// 64x1KB per read (r5: 207us). Fix: W is loaded ONCE into registers.
//
// Block = 1024 threads = 16 waves = 16 code-groups. Lane l of wave g owns
// code g*64+l: its W row lives in 64 VGPRs (one-time coalesced VMEM load),
// its C2 in one VGPR. The block streams its 64 x rows wave-uniformly ->
// s_load broadcast; scalar traffic is now 16.6 KB/block (fits 16KB K$,
// shared by all 16 waves) instead of 1 MB/CU.
//
// Per row: 64-FMA chain acc = fma(x[k](sgpr), w[k](vgpr), acc) — bit-equal
// to the verified fma(xv[k], wr[k], acc) chain (fma is symmetric in a,b);
// dist = (L2 - 2*CL) + C2 per lane; full-wave min butterfly (6x shfl_xor),
// ballot -> lowest lane with dist==min = lowest code index in group (exact
// first-index tie-break); lane 0 stores (min, idx) partial to LDS.
// Final: ascending-g strict-< combine per row = reference's ascending-j scan.
// ---------------------------------------------------------------------------
__global__ void __launch_bounds__(1024, 4)
vq_main_kernel(const float* __restrict__ x, const float* __restrict__ W,
               const float* __restrict__ C2, const float* __restrict__ L2b,
               int* __restrict__ cls_i, float* __restrict__ cls_f) {
    __shared__ float s_pd[16][64];  // [group][row_in_block]
    __shared__ int   s_pi[16][64];

    const int lane = threadIdx.x & 63;
    const int g    = __builtin_amdgcn_readfirstlane(threadIdx.x >> 6);
    const int code = g * 64 + lane;

    // One-time: my code's W row -> 64 VGPRs; its C2 -> 1 VGPR.
    const float* wr = W + (size_t)code * DDIM;
    float wv[64];
#pragma unroll
    for (int k = 0; k < 64; k += 4) {
        float4 v = *(const float4*)(wr + k);
        wv[k] = v.x; wv[k + 1] = v.y; wv[k + 2] = v.z; wv[k + 3] = v.w;
    }
    const float c2v = C2[code];

    const int row0 = blockIdx.x * 64;
#pragma unroll 1
    for (int r = 0; r < 64; ++r) {
        // Block-uniform x row + its L2 -> scalar path (s_load broadcast).
        const float* xrow = x + (size_t)(row0 + r) * DDIM;
        float acc = 0.0f;
#pragma unroll
        for (int k = 0; k < 64; ++k)
            acc = __builtin_fmaf(xrow[k], wv[k], acc);
        const float dist =
            __fadd_rn(__fsub_rn(L2b[row0 + r], __fmul_rn(2.0f, acc)), c2v);

        // Full-wave min (all lanes end with the group min).
        float m = dist;
        m = fminf(m, __shfl_xor(m, 1));
        m = fminf(m, __shfl_xor(m, 2));
        m = fminf(m, __shfl_xor(m, 4));
        m = fminf(m, __shfl_xor(m, 8));
        m = fminf(m, __shfl_xor(m, 16));
        m = fminf(m, __shfl_xor(m, 32));
        const unsigned long long tie = __ballot(dist == m);
        if (lane == 0) {
            s_pd[g][r] = m;
            s_pi[g][r] = g * 64 + (__ffsll((unsigned long long)tie) - 1);
        }
    }
    __syncthreads();

    // Per row: combine 16 group-partials in ascending code order.
    if (threadIdx.x < 64) {
        const int r = threadIdx.x;
        float b  = s_pd[0][r];
        int   bi = s_pi[0][r];
#pragma unroll
        for (int t = 1; t < 16; ++t) {
            const float d = s_pd[t][r];
            if (d < b) { b = d; bi = s_pi[t][r]; }  // ascending j-ranges
        }
        cls_i[row0 + r] = bi;
        cls_f[row0 + r] = (float)bi;  // harness reads indices as fp32
    }
}

// ---------------------------------------------------------------------------
// Kernel 3: gather quantized = W[closest]. 16 threads/row, float4 each.
// ---------------------------------------------------------------------------
__global__ void vq_gather_kernel(const float* __restrict__ W,
                                 const int* __restrict__ cls,
                                 float* __restrict__ outq) {
    const int t = blockIdx.x * blockDim.x + threadIdx.x;
    const int i = t >> 4;
    const int q = t & 15;
    const int j = cls[i];
    const float4 v = *(const float4*)(W + (size_t)j * DDIM + q * 4);
    *(float4*)(outq + (size_t)i * DDIM + q * 4) = v;
}

extern "C" void kernel_launch(void* const* d_in, const int* in_sizes, int n_in,
                              void* d_out, int out_size, void* d_ws, size_t ws_size,
                              hipStream_t stream) {
    const float* x = (const float*)d_in[0];
    const float* W = (const float*)d_in[1];

    float* outq = (float*)d_out;                        // N*D quantized
    float* outi = (float*)d_out + (size_t)NROWS * DDIM; // N indices as float

    float* C2  = (float*)d_ws;                                  // 4 KB
    float* L2b = (float*)((char*)d_ws + 4096);                  // 256 KB
    int*   cls = (int*)((char*)d_ws + 4096 + NROWS * 4);        // 256 KB

    hipLaunchKernelGGL(vq_c2_kernel, dim3(KCB / 256), dim3(256), 0, stream, W, C2);
    hipLaunchKernelGGL(vq_l2_kernel, dim3(NROWS / 256), dim3(256), 0, stream, x, L2b);
    hipLaunchKernelGGL(vq_main_kernel, dim3(NROWS / 64), dim3(1024), 0, stream,
                       x, W, C2, L2b, cls, outi);
    hipLaunchKernelGGL(vq_gather_kernel, dim3((NROWS * 16) / 256), dim3(256), 0,
                       stream, W, cls, outq);
}